// Round 1
// baseline (168.069 us; speedup 1.0000x reference)
//
#include <hip/hip_runtime.h>

#define TPB 256

// pitch-class bitmask of a 4-note row (values are integer-valued floats 0..127)
__device__ __forceinline__ int pcmask(const float4 v) {
    int m = 0;
    m |= 1 << (((int)v.x) % 12);
    m |= 1 << (((int)v.y) % 12);
    m |= 1 << (((int)v.z) % 12);
    m |= 1 << (((int)v.w) % 12);
    return m;
}

// jaccard distance vs a 3-element template mask
__device__ __forceinline__ float jacc(int pm, int tm) {
    float p     = (float)__popc(pm);
    float inter = (float)__popc(pm & tm);
    float uni   = p + 3.0f - inter;
    return 1.0f - inter / (uni + 1e-8f);
}

__global__ void __launch_bounds__(TPB)
chord_loss_kernel(const float4* __restrict__ preds,
                  const float4* __restrict__ targs,
                  int T, int n_win,
                  double* __restrict__ acc) {
    int i = blockIdx.x * TPB + threadIdx.x;
    float sim  = 0.0f;
    float prog = 0.0f;
    if (i < T) {
        int pm = pcmask(preds[i]);
        int tm = pcmask(targs[i]);
        float p     = (float)__popc(pm);
        float q     = (float)__popc(tm);
        float inter = (float)__popc(pm & tm);
        const float eps = 1e-6f;
        float num = inter + eps * (p + q) + 12.0f * eps * eps;
        float den = (p + 12.0f * eps) * (q + 12.0f * eps);
        sim = fminf(fmaxf(num / den, 0.0f), 1.0f);

        if (i < n_win) {
            // windows need pred masks of rows i..i+3 (neighbor rows: L1/L2 hits)
            int m1 = pcmask(preds[i + 1]);
            int m2 = pcmask(preds[i + 2]);
            int m3 = pcmask(preds[i + 3]);
            float maj  = (jacc(pm, 0x091) + jacc(m1, 0x221) +
                          jacc(m2, 0x884) + jacc(m3, 0x091)) * 0.25f;
            float mino = (jacc(pm, 0x089) + jacc(m1, 0x121) +
                          jacc(m2, 0x484) + jacc(m3, 0x089)) * 0.25f;
            prog = fminf(maj, mino);
        }
    }

    // wave64 shuffle reduce (double), then cross-wave via LDS, one atomic pair/block
    double s  = (double)sim;
    double pg = (double)prog;
    #pragma unroll
    for (int off = 32; off > 0; off >>= 1) {
        s  += __shfl_down(s,  off);
        pg += __shfl_down(pg, off);
    }
    __shared__ double ls[TPB / 64], lp[TPB / 64];
    int wid  = threadIdx.x >> 6;
    int lane = threadIdx.x & 63;
    if (lane == 0) { ls[wid] = s; lp[wid] = pg; }
    __syncthreads();
    if (threadIdx.x == 0) {
        double st = 0.0, pt = 0.0;
        #pragma unroll
        for (int w = 0; w < TPB / 64; ++w) { st += ls[w]; pt += lp[w]; }
        atomicAdd(acc,     st);
        atomicAdd(acc + 1, pt);
    }
}

__global__ void finalize_kernel(const double* __restrict__ acc,
                                float* __restrict__ out,
                                int T, int n_win) {
    double sim_mean  = acc[0] / (double)T;
    double prog_mean = acc[1] / (double)n_win;
    out[0] = (float)((1.0 - sim_mean) + 0.5 * prog_mean);
}

extern "C" void kernel_launch(void* const* d_in, const int* in_sizes, int n_in,
                              void* d_out, int out_size, void* d_ws, size_t ws_size,
                              hipStream_t stream) {
    const float4* preds = (const float4*)d_in[0];
    const float4* targs = (const float4*)d_in[1];
    float* out  = (float*)d_out;
    double* acc = (double*)d_ws;

    int T     = in_sizes[0] / 4;   // rows
    int n_win = T - 3;

    hipMemsetAsync(acc, 0, 2 * sizeof(double), stream);

    int blocks = (T + TPB - 1) / TPB;
    chord_loss_kernel<<<blocks, TPB, 0, stream>>>(preds, targs, T, n_win, acc);
    finalize_kernel<<<1, 1, 0, stream>>>(acc, out, T, n_win);
}

// Round 2
// 116.401 us; speedup vs baseline: 1.4439x; 1.4439x over previous
//
#include <hip/hip_runtime.h>

#define TPB  256
#define NBLK 1024   // grid-stride: ~4 rows/thread; atomics 3907->1024 pairs

// pitch-class bitmask of a 4-note row (values are integer-valued floats 0..127)
__device__ __forceinline__ int pcmask(const float4 v) {
    int m = 0;
    m |= 1 << (((int)v.x) % 12);
    m |= 1 << (((int)v.y) % 12);
    m |= 1 << (((int)v.z) % 12);
    m |= 1 << (((int)v.w) % 12);
    return m;
}

// jaccard distance vs a 3-element template mask
__device__ __forceinline__ float jacc(int pm, int tm) {
    float p     = (float)__popc(pm);
    float inter = (float)__popc(pm & tm);
    float uni   = p + 3.0f - inter;
    return 1.0f - inter / (uni + 1e-8f);
}

// d_ws layout: acc[0]=sim sum, acc[1]=prog sum, then a uint completion counter
__global__ void __launch_bounds__(TPB)
chord_loss_kernel(const float4* __restrict__ preds,
                  const float4* __restrict__ targs,
                  int T, int n_win,
                  double* __restrict__ acc,
                  unsigned int* __restrict__ done,
                  float* __restrict__ out) {
    double s  = 0.0;
    double pg = 0.0;
    const int stride = gridDim.x * TPB;
    for (int i = blockIdx.x * TPB + threadIdx.x; i < T; i += stride) {
        float4 pv = preds[i];
        float4 tv = targs[i];
        int pm = pcmask(pv);
        int tm = pcmask(tv);
        float p     = (float)__popc(pm);
        float q     = (float)__popc(tm);
        float inter = (float)__popc(pm & tm);
        const float eps = 1e-6f;
        float num = inter + eps * (p + q) + 12.0f * eps * eps;
        float den = (p + 12.0f * eps) * (q + 12.0f * eps);
        s += (double)fminf(fmaxf(num / den, 0.0f), 1.0f);

        if (i < n_win) {
            // neighbor rows: L1/L2 hits (loaded by neighbor threads anyway)
            int m1 = pcmask(preds[i + 1]);
            int m2 = pcmask(preds[i + 2]);
            int m3 = pcmask(preds[i + 3]);
            float maj  = (jacc(pm, 0x091) + jacc(m1, 0x221) +
                          jacc(m2, 0x884) + jacc(m3, 0x091)) * 0.25f;
            float mino = (jacc(pm, 0x089) + jacc(m1, 0x121) +
                          jacc(m2, 0x484) + jacc(m3, 0x089)) * 0.25f;
            pg += (double)fminf(maj, mino);
        }
    }

    // wave64 shuffle reduce, then cross-wave via LDS, one atomic pair per block
    #pragma unroll
    for (int off = 32; off > 0; off >>= 1) {
        s  += __shfl_down(s,  off);
        pg += __shfl_down(pg, off);
    }
    __shared__ double ls[TPB / 64], lp[TPB / 64];
    int wid  = threadIdx.x >> 6;
    int lane = threadIdx.x & 63;
    if (lane == 0) { ls[wid] = s; lp[wid] = pg; }
    __syncthreads();
    if (threadIdx.x == 0) {
        double st = 0.0, pt = 0.0;
        #pragma unroll
        for (int w = 0; w < TPB / 64; ++w) { st += ls[w]; pt += lp[w]; }
        atomicAdd(acc,     st);
        atomicAdd(acc + 1, pt);
        __threadfence();                       // order my adds before the counter
        unsigned int old = atomicAdd(done, 1u);
        if (old == gridDim.x - 1) {            // I'm the last block: finalize
            double ss = atomicAdd(acc,     0.0);   // read-through-L2
            double pp = atomicAdd(acc + 1, 0.0);
            out[0] = (float)((1.0 - ss / (double)T) + 0.5 * (pp / (double)n_win));
        }
    }
}

extern "C" void kernel_launch(void* const* d_in, const int* in_sizes, int n_in,
                              void* d_out, int out_size, void* d_ws, size_t ws_size,
                              hipStream_t stream) {
    const float4* preds = (const float4*)d_in[0];
    const float4* targs = (const float4*)d_in[1];
    float* out = (float*)d_out;

    double* acc        = (double*)d_ws;
    unsigned int* done = (unsigned int*)((char*)d_ws + 2 * sizeof(double));

    int T     = in_sizes[0] / 4;   // rows
    int n_win = T - 3;

    // zero acc[0..1] + done counter (ws is re-poisoned 0xAA before every launch)
    hipMemsetAsync(d_ws, 0, 2 * sizeof(double) + sizeof(unsigned int), stream);

    chord_loss_kernel<<<NBLK, TPB, 0, stream>>>(preds, targs, T, n_win, acc, done, out);
}

// Round 3
// 83.232 us; speedup vs baseline: 2.0193x; 1.3985x over previous
//
#include <hip/hip_runtime.h>

#define TPB  256
#define NBLK 2048   // 8 blocks/CU -> 32 waves/CU (100% occupancy cap)

// pitch-class bitmask of a 4-note row. Values are integer-valued floats in
// [0,128); x%12 == x - 12*((x*683)>>13) exactly for 0<=x<=127.
__device__ __forceinline__ int pcmask(const float4 v) {
    int a = (int)v.x, b = (int)v.y, c = (int)v.z, d = (int)v.w;
    a -= 12 * ((a * 683) >> 13);
    b -= 12 * ((b * 683) >> 13);
    c -= 12 * ((c * 683) >> 13);
    d -= 12 * ((d * 683) >> 13);
    return (1 << a) | (1 << b) | (1 << c) | (1 << d);
}

// jaccard distance vs a 3-element template mask
__device__ __forceinline__ float jacc(int pm, int tm) {
    float p     = (float)__popc(pm);
    float inter = (float)__popc(pm & tm);
    float uni   = p + 3.0f - inter;
    return 1.0f - inter / (uni + 1e-8f);
}

// Stage 1: each wave owns contiguous 64-row chunks (grid-stride). Neighbor
// pred-masks come from __shfl_down; lanes 61-63 load the 1-3 boundary rows.
// Each block writes one double2 partial to its own ws slot (no atomics).
__global__ void __launch_bounds__(TPB)
chord_partial_kernel(const float4* __restrict__ preds,
                     const float4* __restrict__ targs,
                     int T, int n_win,
                     double2* __restrict__ partials) {
    const int lane   = threadIdx.x & 63;
    const int gwave  = blockIdx.x * (TPB / 64) + (threadIdx.x >> 6);
    const int nwaves = NBLK * (TPB / 64);

    double s = 0.0, pg = 0.0;

    for (int base = gwave * 64; base < T; base += nwaves * 64) {
        int  i     = base + lane;
        bool valid = (i < T);
        int  pm = 0, tm = 0;
        if (valid) {
            float4 pv = preds[i];
            float4 tv = targs[i];
            pm = pcmask(pv);
            tm = pcmask(tv);
            float p     = (float)__popc(pm);
            float q     = (float)__popc(tm);
            float inter = (float)__popc(pm & tm);
            const float eps = 1e-6f;
            float num = inter + eps * (p + q) + 12.0f * eps * eps;
            float den = (p + 12.0f * eps) * (q + 12.0f * eps);
            s += (double)fminf(fmaxf(num / den, 0.0f), 1.0f);
        }

        // neighbor masks via cross-lane (uniform execution for shuffles)
        int m1 = __shfl_down(pm, 1);
        int m2 = __shfl_down(pm, 2);
        int m3 = __shfl_down(pm, 3);

        if (i < n_win) {
            if (lane >= 63) m1 = pcmask(preds[i + 1]);   // lanes whose shuffle
            if (lane >= 62) m2 = pcmask(preds[i + 2]);   // crossed the wave
            if (lane >= 61) m3 = pcmask(preds[i + 3]);   // boundary
            float maj  = (jacc(pm, 0x091) + jacc(m1, 0x221) +
                          jacc(m2, 0x884) + jacc(m3, 0x091)) * 0.25f;
            float mino = (jacc(pm, 0x089) + jacc(m1, 0x121) +
                          jacc(m2, 0x484) + jacc(m3, 0x089)) * 0.25f;
            pg += (double)fminf(maj, mino);
        }
    }

    // block reduction: wave shuffle, then LDS across waves
    #pragma unroll
    for (int off = 32; off > 0; off >>= 1) {
        s  += __shfl_down(s,  off);
        pg += __shfl_down(pg, off);
    }
    __shared__ double ls[TPB / 64], lp[TPB / 64];
    int wid = threadIdx.x >> 6;
    if (lane == 0) { ls[wid] = s; lp[wid] = pg; }
    __syncthreads();
    if (threadIdx.x == 0) {
        double st = 0.0, pt = 0.0;
        #pragma unroll
        for (int w = 0; w < TPB / 64; ++w) { st += ls[w]; pt += lp[w]; }
        partials[blockIdx.x] = make_double2(st, pt);
    }
}

// Stage 2: one block reduces the 2048 partials and writes the scalar.
__global__ void __launch_bounds__(TPB)
chord_final_kernel(const double2* __restrict__ partials,
                   float* __restrict__ out, int T, int n_win) {
    double s = 0.0, pg = 0.0;
    for (int t = threadIdx.x; t < NBLK; t += TPB) {
        double2 v = partials[t];
        s  += v.x;
        pg += v.y;
    }
    #pragma unroll
    for (int off = 32; off > 0; off >>= 1) {
        s  += __shfl_down(s,  off);
        pg += __shfl_down(pg, off);
    }
    __shared__ double ls[TPB / 64], lp[TPB / 64];
    int wid = threadIdx.x >> 6, lane = threadIdx.x & 63;
    if (lane == 0) { ls[wid] = s; lp[wid] = pg; }
    __syncthreads();
    if (threadIdx.x == 0) {
        double st = 0.0, pt = 0.0;
        #pragma unroll
        for (int w = 0; w < TPB / 64; ++w) { st += ls[w]; pt += lp[w]; }
        out[0] = (float)((1.0 - st / (double)T) + 0.5 * (pt / (double)n_win));
    }
}

extern "C" void kernel_launch(void* const* d_in, const int* in_sizes, int n_in,
                              void* d_out, int out_size, void* d_ws, size_t ws_size,
                              hipStream_t stream) {
    const float4* preds = (const float4*)d_in[0];
    const float4* targs = (const float4*)d_in[1];
    float* out = (float*)d_out;
    double2* partials = (double2*)d_ws;   // NBLK double2 slots, fully overwritten

    int T     = in_sizes[0] / 4;   // rows
    int n_win = T - 3;

    chord_partial_kernel<<<NBLK, TPB, 0, stream>>>(preds, targs, T, n_win, partials);
    chord_final_kernel<<<1, TPB, 0, stream>>>(partials, out, T, n_win);
}